// Round 1
// baseline (142.657 us; speedup 1.0000x reference)
//
#include <hip/hip_runtime.h>

#define NQ 11
#define NL 3
#define S  2048
#define NB 8
#define NA 96
#define NF 64
#define PADW 100

__device__ __forceinline__ float sigmoidf_(float x) { return 1.0f / (1.0f + expf(-x)); }

// One block per node (atom): feature MLP -> real statevector circuit in LDS ->
// weighted atomic accumulation into R[b][s].
__global__ __launch_bounds__(256) void circuit_kernel(
    const float* __restrict__ nf,     // [NB*NA, NF]
    const float* __restrict__ W1,     // [64,100]
    const float* __restrict__ b1,     // [64]
    const float* __restrict__ W2,     // [11,64]
    const float* __restrict__ b2,     // [11]
    const float* __restrict__ rot,    // [NL,NQ,3]
    const float* __restrict__ ent,    // [NL,NQ-1]
    const float* __restrict__ pool_w, // [11]
    float* __restrict__ Racc)         // [NB, S]
{
    __shared__ float amps[S];
    __shared__ float hbuf[64];
    __shared__ float fq[NQ];

    const int node = blockIdx.x;          // 0..767
    const int tid  = threadIdx.x;
    const int b    = node / NA;
    const int a    = node % NA;

    // ---- feature preprocessor: h = relu(x @ W1[:, :64]^T + b1) (pad cols are zero) ----
    if (tid < 64) {
        float acc = b1[tid];
        const float* xrow = nf + node * NF;
        const float* wrow = W1 + tid * PADW;
#pragma unroll
        for (int k = 0; k < NF; ++k) acc += xrow[k] * wrow[k];
        hbuf[tid] = fmaxf(acc, 0.0f);
    }
    __syncthreads();
    // ---- f = tanh(h @ W2^T + b2) ----
    if (tid < NQ) {
        float acc = b2[tid];
        const float* wrow = W2 + tid * 64;
#pragma unroll
        for (int k = 0; k < 64; ++k) acc += hbuf[k] * wrow[k];
        fq[tid] = tanhf(acc);
    }
    // ---- init statevector |0> ----
    for (int i = tid; i < S; i += 256) amps[i] = (i == 0) ? 1.0f : 0.0f;
    __syncthreads();

    // ---- feature-map circuit (all-real amplitudes) ----
    for (int l = 0; l < NL; ++l) {
        // single-qubit rotations
        for (int q = 0; q < NQ; ++q) {
            const float f = fq[q];
            const float* r = rot + (l * NQ + q) * 3;
            const float hx = 0.5f * r[0] * f;
            const float hy = 0.5f * r[1] * f;
            const float hz = 0.5f * r[2] * f;
            const float cx = cosf(hx), sx = sinf(hx);
            const float cy = cosf(hy), sy = sinf(hy);
            const float cz = cosf(hz), sz = sinf(hz);
            const float m00 = cx * cy * cz, m01 = -sx * sy * sz;
            const float m10 = sx * sy * cz, m11 = cx * cy * sz;
            const int lo = 1 << q;
#pragma unroll
            for (int i = 0; i < 4; ++i) {
                const int p  = tid + 256 * i;              // pair index 0..1023
                const int s0 = ((p >> q) << (q + 1)) | (p & (lo - 1));
                const int s1 = s0 | lo;
                const float a0 = amps[s0], a1 = amps[s1];
                amps[s0] = m00 * a0 + m01 * a1;
                amps[s1] = m10 * a0 + m11 * a1;
            }
            __syncthreads();
        }
        // parameterized-CNOT entanglement: states with bit q == 1 mix with
        // partner (bit q+1 flipped); symmetric pair update from OLD values.
        for (int q = 0; q < NQ - 1; ++q) {
            const float p = sigmoidf_(ent[l * (NQ - 1) + q]);
            const int lo = 1 << q;
#pragma unroll
            for (int i = 0; i < 2; ++i) {
                const int t    = tid + 256 * i;            // pair index 0..511
                const int low  = t & (lo - 1);
                const int rest = t >> q;
                const int s0 = (rest << (q + 2)) | lo | low;   // bit q =1, bit q+1 =0
                const int s1 = s0 | (lo << 1);                 // bit q+1 flipped
                const float a0 = amps[s0], a1 = amps[s1];
                amps[s0] = (1.0f - p) * a0 + p * a1;
                amps[s1] = (1.0f - p) * a1 + p * a0;
            }
            __syncthreads();
        }
    }

    // ---- pooled accumulation: R[b][s] += sigmoid(pool_w[a%11]) * amps[s] ----
    const float w = sigmoidf_(pool_w[a % NQ]);
    float* Rb = Racc + b * S;
    for (int i = tid; i < S; i += 256) atomicAdd(&Rb[i], w * amps[i]);
}

// One block per batch element: phase-weighted sums over states, then 22->256->128->64 MLP.
__global__ __launch_bounds__(256) void pool_mlp_kernel(
    const float* __restrict__ Racc,   // [NB, S]
    const float* __restrict__ msg,    // [NL,NQ,3]
    const float* __restrict__ Wo1, const float* __restrict__ bo1,  // [256,22],[256]
    const float* __restrict__ Wo2, const float* __restrict__ bo2,  // [128,256],[128]
    const float* __restrict__ Wo3, const float* __restrict__ bo3,  // [64,128],[64]
    float* __restrict__ out)          // [NB,64]
{
    __shared__ float Theta[NQ];
    __shared__ float red[3][4];
    __shared__ float rm_sh, im_sh;
    __shared__ float h1[256];
    __shared__ float h2[128];

    const int b   = blockIdx.x;
    const int tid = threadIdx.x;

    if (tid < NQ) {
        float t = 0.0f;
        for (int l = 0; l < NL; ++l)
#pragma unroll
            for (int c = 0; c < 3; ++c) t += msg[(l * NQ + tid) * 3 + c];
        Theta[tid] = t;
    }
    __syncthreads();

    float psq = 0.0f, pc = 0.0f, ps = 0.0f;
    const float* Rb = Racc + b * S;
    for (int s = tid; s < S; s += 256) {
        const float R = Rb[s];
        float phi = 0.0f;
#pragma unroll
        for (int q = 0; q < NQ; ++q)
            if ((s >> q) & 1) phi += Theta[q];
        psq += R * R;
        pc  += R * cosf(phi);
        ps  += R * sinf(phi);
    }
    // wave (64-lane) reduction, then cross-wave via LDS
#pragma unroll
    for (int off = 32; off >= 1; off >>= 1) {
        psq += __shfl_down(psq, off, 64);
        pc  += __shfl_down(pc,  off, 64);
        ps  += __shfl_down(ps,  off, 64);
    }
    const int lane = tid & 63, wave = tid >> 6;
    if (lane == 0) { red[0][wave] = psq; red[1][wave] = pc; red[2][wave] = ps; }
    __syncthreads();
    if (tid == 0) {
        const float sq = red[0][0] + red[0][1] + red[0][2] + red[0][3];
        const float sc = red[1][0] + red[1][1] + red[1][2] + red[1][3];
        const float ss = red[2][0] + red[2][1] + red[2][2] + red[2][3];
        const float norm = fmaxf(sqrtf(sq), 1e-12f);
        rm_sh = sc / (float)S / norm;
        im_sh = ss / (float)S / norm;
    }
    __syncthreads();
    const float rm = rm_sh, im = im_sh;

    // h1[j] = relu(rm * sum(Wo1[j,0:11]) + im * sum(Wo1[j,11:22]) + bo1[j])
    {
        float s1 = 0.0f, s2 = 0.0f;
        const float* wrow = Wo1 + tid * (2 * NQ);
#pragma unroll
        for (int k = 0; k < NQ; ++k)       s1 += wrow[k];
#pragma unroll
        for (int k = NQ; k < 2 * NQ; ++k)  s2 += wrow[k];
        h1[tid] = fmaxf(rm * s1 + im * s2 + bo1[tid], 0.0f);
    }
    __syncthreads();
    if (tid < 128) {
        float acc = bo2[tid];
        const float* wrow = Wo2 + tid * 256;
        for (int k = 0; k < 256; ++k) acc += h1[k] * wrow[k];
        h2[tid] = fmaxf(acc, 0.0f);
    }
    __syncthreads();
    if (tid < 64) {
        float acc = bo3[tid];
        const float* wrow = Wo3 + tid * 128;
        for (int k = 0; k < 128; ++k) acc += h2[k] * wrow[k];
        out[b * 64 + tid] = acc;
    }
}

extern "C" void kernel_launch(void* const* d_in, const int* in_sizes, int n_in,
                              void* d_out, int out_size, void* d_ws, size_t ws_size,
                              hipStream_t stream) {
    const float* nf     = (const float*)d_in[0];
    // d_in[1] = edge_indices (unused by the math)
    const float* W1     = (const float*)d_in[2];
    const float* b1     = (const float*)d_in[3];
    const float* W2     = (const float*)d_in[4];
    const float* b2     = (const float*)d_in[5];
    const float* rot    = (const float*)d_in[6];
    const float* ent    = (const float*)d_in[7];
    const float* msg    = (const float*)d_in[8];
    const float* pool_w = (const float*)d_in[9];
    const float* Wo1    = (const float*)d_in[10];
    const float* bo1    = (const float*)d_in[11];
    const float* Wo2    = (const float*)d_in[12];
    const float* bo2    = (const float*)d_in[13];
    const float* Wo3    = (const float*)d_in[14];
    const float* bo3    = (const float*)d_in[15];

    float* Racc = (float*)d_ws;                       // [NB, S] accumulator
    hipMemsetAsync(Racc, 0, NB * S * sizeof(float), stream);

    circuit_kernel<<<dim3(NB * NA), dim3(256), 0, stream>>>(
        nf, W1, b1, W2, b2, rot, ent, pool_w, Racc);

    pool_mlp_kernel<<<dim3(NB), dim3(256), 0, stream>>>(
        Racc, msg, Wo1, bo1, Wo2, bo2, Wo3, bo3, (float*)d_out);
}

// Round 2
// 124.794 us; speedup vs baseline: 1.1431x; 1.1431x over previous
//
#include <hip/hip_runtime.h>

#define NQ 11
#define NL 3
#define S  2048
#define NB 8
#define NA 96
#define NF 64
#define PADW 100
#define WPB 4   // waves (nodes) per block

__device__ __forceinline__ float sigmoidf_(float x) { return 1.0f / (1.0f + expf(-x)); }

// One WAVE per node. Statevector held in registers: state = (i<<6) | lane,
// i = per-lane register index (qubits 6..10), lane = qubits 0..5.
// No __syncthreads in the circuit; cross-lane via shfl only.
__global__ __launch_bounds__(256) void circuit_kernel(
    const float* __restrict__ nf,     // [NB*NA, NF]
    const float* __restrict__ W1,     // [64,100]
    const float* __restrict__ b1,     // [64]
    const float* __restrict__ W2,     // [11,64]
    const float* __restrict__ b2,     // [11]
    const float* __restrict__ rot,    // [NL,NQ,3]
    const float* __restrict__ ent,    // [NL,NQ-1]
    const float* __restrict__ pool_w, // [11]
    float* __restrict__ Racc)         // [NB, S]
{
    __shared__ float W1s[64 * 65];    // stride-65 pad: bank=(row+col)%32 -> 2-way (free)
    __shared__ float xs[WPB][64];

    const int tid   = threadIdx.x;
    const int lane  = tid & 63;
    const int wave  = tid >> 6;
    const int node0 = blockIdx.x * WPB;
    const int node  = node0 + wave;
    const int b     = node / NA;
    const int a     = node % NA;

    // ---- stage W1[:, 0:64] into padded LDS (coalesced float4 loads) ----
    {
        const int r  = tid >> 2;
        const int c0 = (tid & 3) << 4;
        const float4* src = reinterpret_cast<const float4*>(W1 + r * PADW + c0);
        float* dst = &W1s[r * 65 + c0];
#pragma unroll
        for (int j = 0; j < 4; ++j) {
            const float4 vv = src[j];
            dst[4 * j + 0] = vv.x; dst[4 * j + 1] = vv.y;
            dst[4 * j + 2] = vv.z; dst[4 * j + 3] = vv.w;
        }
        xs[wave][lane] = nf[node0 * NF + tid];   // 256 contiguous floats
    }
    __syncthreads();

    // ---- h[lane] = relu(b1 + sum_k x[k]*W1[lane,k]) ; xs read is LDS broadcast ----
    float h = b1[lane];
    {
        const float* wrow = &W1s[lane * 65];
        const float* xv   = xs[wave];
#pragma unroll
        for (int k = 0; k < 64; ++k) h = fmaf(wrow[k], xv[k], h);
    }
    h = fmaxf(h, 0.0f);

    // ---- f[q] = tanh(b2[q] + sum_k h[k]*W2[q,k]) via wave butterfly; lane q keeps it ----
    float fscal = 0.0f;
#pragma unroll
    for (int q = 0; q < NQ; ++q) {
        float t = h * W2[q * 64 + lane];
#pragma unroll
        for (int off = 32; off >= 1; off >>= 1) t += __shfl_xor(t, off, 64);
        if (lane == q) fscal = tanhf(t + b2[q]);
    }

    // ---- per-lane gate-matrix precompute: lane g<33 owns gate g=(l*11+q) ----
    const int qidx = lane < 11 ? lane : (lane < 22 ? lane - 11 : (lane < 33 ? lane - 22 : 0));
    const float fg = __shfl(fscal, qidx, 64);
    float m00 = 0.f, m01 = 0.f, m10 = 0.f, m11 = 0.f;
    if (lane < NL * NQ) {
        const float* r = rot + lane * 3;
        const float hx = 0.5f * r[0] * fg;
        const float hy = 0.5f * r[1] * fg;
        const float hz = 0.5f * r[2] * fg;
        const float cx = cosf(hx), sx = sinf(hx);
        const float cy = cosf(hy), sy = sinf(hy);
        const float cz = cosf(hz), sz = sinf(hz);
        m00 = cx * cy * cz; m01 = -sx * sy * sz;
        m10 = sx * sy * cz; m11 = cx * cy * sz;
    }
    float pent = 0.0f;
    if (lane < NL * (NQ - 1)) pent = sigmoidf_(ent[lane]);

    // ---- register statevector ----
    float v[32];
#pragma unroll
    for (int i = 0; i < 32; ++i) v[i] = 0.0f;
    if (lane == 0) v[0] = 1.0f;

    for (int l = 0; l < NL; ++l) {
        // single-qubit rotations
#pragma unroll
        for (int q = 0; q < NQ; ++q) {
            const int g = l * NQ + q;
            const float g00 = __shfl(m00, g, 64);
            const float g01 = __shfl(m01, g, 64);
            const float g10 = __shfl(m10, g, 64);
            const float g11 = __shfl(m11, g, 64);
            if (q < 6) {
                // partner in lane^ (1<<q); coefficient pick by own bit
                const int   bit = (lane >> q) & 1;
                const float c0  = bit ? g10 : g01;   // multiplies partner value
                const float c1  = bit ? g11 : g00;   // multiplies own value
#pragma unroll
                for (int i = 0; i < 32; ++i) {
                    const float pv = __shfl_xor(v[i], 1 << q, 64);
                    v[i] = fmaf(c0, pv, c1 * v[i]);
                }
            } else {
                // in-register pairs on bit (q-6)
                const int rb = 1 << (q - 6);
#pragma unroll
                for (int j = 0; j < 16; ++j) {
                    const int i0 = ((j >> (q - 6)) << (q - 5)) | (j & (rb - 1));
                    const int i1 = i0 | rb;
                    const float a0 = v[i0], a1 = v[i1];
                    v[i0] = fmaf(g00, a0, g01 * a1);
                    v[i1] = fmaf(g10, a0, g11 * a1);
                }
            }
        }
        // parameterized-CNOT entanglement: ctrl bit q, partner flips bit q+1
#pragma unroll
        for (int q = 0; q < NQ - 1; ++q) {
            const float p = __shfl(pent, l * (NQ - 1) + q, 64);
            if (q < 5) {
                // ctrl = lane bit q; partner lane ^ (1<<(q+1))
                const int act = (lane >> q) & 1;
#pragma unroll
                for (int i = 0; i < 32; ++i) {
                    const float pv = __shfl_xor(v[i], 1 << (q + 1), 64);
                    const float nv = fmaf(p, pv - v[i], v[i]);
                    v[i] = act ? nv : v[i];
                }
            } else if (q == 5) {
                // ctrl = lane bit 5; partner flips reg bit 0 (i^1)
                const int act = (lane >> 5) & 1;
#pragma unroll
                for (int j = 0; j < 16; ++j) {
                    const int i0 = 2 * j, i1 = 2 * j + 1;
                    const float d   = v[i1] - v[i0];
                    const float nv0 = fmaf(p, d, v[i0]);
                    const float nv1 = fmaf(-p, d, v[i1]);
                    v[i0] = act ? nv0 : v[i0];
                    v[i1] = act ? nv1 : v[i1];
                }
            } else {
                // ctrl = reg bit (q-6) == 1; partner flips reg bit (q-5); in-register
                const int cb = q - 6;
#pragma unroll
                for (int j = 0; j < 8; ++j) {
                    const int i0 = ((j >> cb) << (cb + 2)) | (1 << cb) | (j & ((1 << cb) - 1));
                    const int i1 = i0 | (1 << (cb + 1));
                    const float d = v[i1] - v[i0];
                    v[i0] = fmaf(p, d, v[i0]);
                    v[i1] = fmaf(-p, d, v[i1]);
                }
            }
        }
    }

    // ---- weighted accumulation; per-instruction addresses are 64 consecutive floats ----
    const float w = sigmoidf_(pool_w[a % NQ]);
    float* Rb = Racc + b * S;
#pragma unroll
    for (int i = 0; i < 32; ++i)
        atomicAdd(&Rb[(i << 6) | lane], w * v[i]);
}

// One block per batch element: phase-weighted sums over states, then 22->256->128->64 MLP.
__global__ __launch_bounds__(256) void pool_mlp_kernel(
    const float* __restrict__ Racc,   // [NB, S]
    const float* __restrict__ msg,    // [NL,NQ,3]
    const float* __restrict__ Wo1, const float* __restrict__ bo1,  // [256,22],[256]
    const float* __restrict__ Wo2, const float* __restrict__ bo2,  // [128,256],[128]
    const float* __restrict__ Wo3, const float* __restrict__ bo3,  // [64,128],[64]
    float* __restrict__ out)          // [NB,64]
{
    __shared__ float Theta[NQ];
    __shared__ float red[3][4];
    __shared__ float rm_sh, im_sh;
    __shared__ float h1[256];
    __shared__ float h2[128];

    const int b   = blockIdx.x;
    const int tid = threadIdx.x;

    if (tid < NQ) {
        float t = 0.0f;
        for (int l = 0; l < NL; ++l)
#pragma unroll
            for (int c = 0; c < 3; ++c) t += msg[(l * NQ + tid) * 3 + c];
        Theta[tid] = t;
    }
    __syncthreads();

    float psq = 0.0f, pc = 0.0f, ps = 0.0f;
    const float* Rb = Racc + b * S;
    for (int s = tid; s < S; s += 256) {
        const float R = Rb[s];
        float phi = 0.0f;
#pragma unroll
        for (int q = 0; q < NQ; ++q)
            if ((s >> q) & 1) phi += Theta[q];
        psq += R * R;
        pc  += R * cosf(phi);
        ps  += R * sinf(phi);
    }
#pragma unroll
    for (int off = 32; off >= 1; off >>= 1) {
        psq += __shfl_down(psq, off, 64);
        pc  += __shfl_down(pc,  off, 64);
        ps  += __shfl_down(ps,  off, 64);
    }
    const int lane = tid & 63, wave = tid >> 6;
    if (lane == 0) { red[0][wave] = psq; red[1][wave] = pc; red[2][wave] = ps; }
    __syncthreads();
    if (tid == 0) {
        const float sq = red[0][0] + red[0][1] + red[0][2] + red[0][3];
        const float sc = red[1][0] + red[1][1] + red[1][2] + red[1][3];
        const float ss = red[2][0] + red[2][1] + red[2][2] + red[2][3];
        const float norm = fmaxf(sqrtf(sq), 1e-12f);
        rm_sh = sc / (float)S / norm;
        im_sh = ss / (float)S / norm;
    }
    __syncthreads();
    const float rm = rm_sh, im = im_sh;

    {
        float s1 = 0.0f, s2 = 0.0f;
        const float* wrow = Wo1 + tid * (2 * NQ);
#pragma unroll
        for (int k = 0; k < NQ; ++k)       s1 += wrow[k];
#pragma unroll
        for (int k = NQ; k < 2 * NQ; ++k)  s2 += wrow[k];
        h1[tid] = fmaxf(rm * s1 + im * s2 + bo1[tid], 0.0f);
    }
    __syncthreads();
    if (tid < 128) {
        float acc = bo2[tid];
        const float* wrow = Wo2 + tid * 256;
        for (int k = 0; k < 256; ++k) acc += h1[k] * wrow[k];
        h2[tid] = fmaxf(acc, 0.0f);
    }
    __syncthreads();
    if (tid < 64) {
        float acc = bo3[tid];
        const float* wrow = Wo3 + tid * 128;
        for (int k = 0; k < 128; ++k) acc += h2[k] * wrow[k];
        out[b * 64 + tid] = acc;
    }
}

extern "C" void kernel_launch(void* const* d_in, const int* in_sizes, int n_in,
                              void* d_out, int out_size, void* d_ws, size_t ws_size,
                              hipStream_t stream) {
    const float* nf     = (const float*)d_in[0];
    // d_in[1] = edge_indices (unused by the math)
    const float* W1     = (const float*)d_in[2];
    const float* b1     = (const float*)d_in[3];
    const float* W2     = (const float*)d_in[4];
    const float* b2     = (const float*)d_in[5];
    const float* rot    = (const float*)d_in[6];
    const float* ent    = (const float*)d_in[7];
    const float* msg    = (const float*)d_in[8];
    const float* pool_w = (const float*)d_in[9];
    const float* Wo1    = (const float*)d_in[10];
    const float* bo1    = (const float*)d_in[11];
    const float* Wo2    = (const float*)d_in[12];
    const float* bo2    = (const float*)d_in[13];
    const float* Wo3    = (const float*)d_in[14];
    const float* bo3    = (const float*)d_in[15];

    float* Racc = (float*)d_ws;                       // [NB, S] accumulator
    hipMemsetAsync(Racc, 0, NB * S * sizeof(float), stream);

    circuit_kernel<<<dim3(NB * NA / WPB), dim3(256), 0, stream>>>(
        nf, W1, b1, W2, b2, rot, ent, pool_w, Racc);

    pool_mlp_kernel<<<dim3(NB), dim3(256), 0, stream>>>(
        Racc, msg, Wo1, bo1, Wo2, bo2, Wo3, bo3, (float*)d_out);
}

// Round 3
// 122.983 us; speedup vs baseline: 1.1600x; 1.0147x over previous
//
#include <hip/hip_runtime.h>

#define NQ 11
#define NL 3
#define S  2048
#define NB 8
#define NA 96
#define NF 64
#define PADW 100
#define WPB 4            // waves (nodes) per block
#define PPB (NA / WPB)   // partial blocks per batch = 24

__device__ __forceinline__ float sigmoidf_(float x) { return 1.0f / (1.0f + expf(-x)); }

// One WAVE per node. Statevector in registers: state = (i<<6) | lane,
// i = per-lane register index (qubits 6..10), lane = qubits 0..5.
// Block reduces its 4 nodes in LDS and stores ONE partial vector (no atomics).
__global__ __launch_bounds__(256) void circuit_kernel(
    const float* __restrict__ nf,     // [NB*NA, NF]
    const float* __restrict__ W1,     // [64,100]
    const float* __restrict__ b1,     // [64]
    const float* __restrict__ W2,     // [11,64]
    const float* __restrict__ b2,     // [11]
    const float* __restrict__ rot,    // [NL,NQ,3]
    const float* __restrict__ ent,    // [NL,NQ-1]
    const float* __restrict__ pool_w, // [11]
    float* __restrict__ Rpart)        // [NB*NA/WPB, S]
{
    __shared__ float W1s[64 * 65];    // stride-65 pad: 2-way bank alias (free)
    __shared__ float xs[WPB][64];
    __shared__ float psum[WPB][S];

    const int tid   = threadIdx.x;
    const int lane  = tid & 63;
    const int wave  = tid >> 6;
    const int node0 = blockIdx.x * WPB;
    const int node  = node0 + wave;
    const int a     = node % NA;

    // ---- stage W1[:, 0:64] into padded LDS (coalesced float4 loads) ----
    {
        const int r  = tid >> 2;
        const int c0 = (tid & 3) << 4;
        const float4* src = reinterpret_cast<const float4*>(W1 + r * PADW + c0);
        float* dst = &W1s[r * 65 + c0];
#pragma unroll
        for (int j = 0; j < 4; ++j) {
            const float4 vv = src[j];
            dst[4 * j + 0] = vv.x; dst[4 * j + 1] = vv.y;
            dst[4 * j + 2] = vv.z; dst[4 * j + 3] = vv.w;
        }
        xs[wave][lane] = nf[node0 * NF + tid];   // 256 contiguous floats
    }
    __syncthreads();

    // ---- h[lane] = relu(b1 + sum_k x[k]*W1[lane,k]) ----
    float h = b1[lane];
    {
        const float* wrow = &W1s[lane * 65];
        const float* xv   = xs[wave];
#pragma unroll
        for (int k = 0; k < 64; ++k) h = fmaf(wrow[k], xv[k], h);
    }
    h = fmaxf(h, 0.0f);

    // ---- f[q] = tanh(b2[q] + sum_k h[k]*W2[q,k]) via wave butterfly ----
    float fscal = 0.0f;
#pragma unroll
    for (int q = 0; q < NQ; ++q) {
        float t = h * W2[q * 64 + lane];
#pragma unroll
        for (int off = 32; off >= 1; off >>= 1) t += __shfl_xor(t, off, 64);
        if (lane == q) fscal = tanhf(t + b2[q]);
    }

    // ---- per-lane gate-matrix precompute: lane g<33 owns gate g=(l*11+q) ----
    const int qidx = lane < 11 ? lane : (lane < 22 ? lane - 11 : (lane < 33 ? lane - 22 : 0));
    const float fg = __shfl(fscal, qidx, 64);
    float m00 = 0.f, m01 = 0.f, m10 = 0.f, m11 = 0.f;
    if (lane < NL * NQ) {
        const float* r = rot + lane * 3;
        const float hx = 0.5f * r[0] * fg;
        const float hy = 0.5f * r[1] * fg;
        const float hz = 0.5f * r[2] * fg;
        const float cx = cosf(hx), sx = sinf(hx);
        const float cy = cosf(hy), sy = sinf(hy);
        const float cz = cosf(hz), sz = sinf(hz);
        m00 = cx * cy * cz; m01 = -sx * sy * sz;
        m10 = sx * sy * cz; m11 = cx * cy * sz;
    }
    float pent = 0.0f;
    if (lane < NL * (NQ - 1)) pent = sigmoidf_(ent[lane]);

    // ---- register statevector ----
    float v[32];
#pragma unroll
    for (int i = 0; i < 32; ++i) v[i] = 0.0f;
    if (lane == 0) v[0] = 1.0f;

    for (int l = 0; l < NL; ++l) {
        // single-qubit rotations
#pragma unroll
        for (int q = 0; q < NQ; ++q) {
            const int g = l * NQ + q;
            const float g00 = __shfl(m00, g, 64);
            const float g01 = __shfl(m01, g, 64);
            const float g10 = __shfl(m10, g, 64);
            const float g11 = __shfl(m11, g, 64);
            if (q < 6) {
                const int   bit = (lane >> q) & 1;
                const float c0  = bit ? g10 : g01;   // multiplies partner value
                const float c1  = bit ? g11 : g00;   // multiplies own value
#pragma unroll
                for (int i = 0; i < 32; ++i) {
                    const float pv = __shfl_xor(v[i], 1 << q, 64);
                    v[i] = fmaf(c0, pv, c1 * v[i]);
                }
            } else {
                const int rb = 1 << (q - 6);
#pragma unroll
                for (int j = 0; j < 16; ++j) {
                    const int i0 = ((j >> (q - 6)) << (q - 5)) | (j & (rb - 1));
                    const int i1 = i0 | rb;
                    const float a0 = v[i0], a1 = v[i1];
                    v[i0] = fmaf(g00, a0, g01 * a1);
                    v[i1] = fmaf(g10, a0, g11 * a1);
                }
            }
        }
        // parameterized-CNOT entanglement: ctrl bit q, partner flips bit q+1
#pragma unroll
        for (int q = 0; q < NQ - 1; ++q) {
            const float p = __shfl(pent, l * (NQ - 1) + q, 64);
            if (q < 5) {
                // fold ctrl select into coefficient: pact = p for ctrl==1 lanes else 0
                const float pact = p * (float)((lane >> q) & 1);
#pragma unroll
                for (int i = 0; i < 32; ++i) {
                    const float pv = __shfl_xor(v[i], 1 << (q + 1), 64);
                    v[i] = fmaf(pact, pv - v[i], v[i]);
                }
            } else if (q == 5) {
                const float pact = p * (float)((lane >> 5) & 1);
#pragma unroll
                for (int j = 0; j < 16; ++j) {
                    const int i0 = 2 * j, i1 = 2 * j + 1;
                    const float d = v[i1] - v[i0];
                    v[i0] = fmaf(pact, d, v[i0]);
                    v[i1] = fmaf(-pact, d, v[i1]);
                }
            } else {
                const int cb = q - 6;
#pragma unroll
                for (int j = 0; j < 8; ++j) {
                    const int i0 = ((j >> cb) << (cb + 2)) | (1 << cb) | (j & ((1 << cb) - 1));
                    const int i1 = i0 | (1 << (cb + 1));
                    const float d = v[i1] - v[i0];
                    v[i0] = fmaf(p, d, v[i0]);
                    v[i1] = fmaf(-p, d, v[i1]);
                }
            }
        }
    }

    // ---- block-local reduction, then ONE plain-store partial per block ----
    const float w = sigmoidf_(pool_w[a % NQ]);
#pragma unroll
    for (int i = 0; i < 32; ++i) psum[wave][(i << 6) | lane] = w * v[i];
    __syncthreads();
    float* Rb = Rpart + blockIdx.x * S;
    for (int s = tid; s < S; s += 256)
        Rb[s] = psum[0][s] + psum[1][s] + psum[2][s] + psum[3][s];
}

// One block per batch: sum 24 partials, phase-weighted sums, 22->256->128->64 MLP.
__global__ __launch_bounds__(1024) void pool_mlp_kernel(
    const float* __restrict__ Rpart,  // [NB*PPB, S]
    const float* __restrict__ msg,    // [NL,NQ,3]
    const float* __restrict__ Wo1, const float* __restrict__ bo1,  // [256,22],[256]
    const float* __restrict__ Wo2, const float* __restrict__ bo2,  // [128,256],[128]
    const float* __restrict__ Wo3, const float* __restrict__ bo3,  // [64,128],[64]
    float* __restrict__ out)          // [NB,64]
{
    __shared__ float Theta[NQ];
    __shared__ float red[3][16];
    __shared__ float rm_sh, im_sh;
    __shared__ float h1[256];
    __shared__ float h2[128];

    const int b   = blockIdx.x;
    const int tid = threadIdx.x;

    if (tid < NQ) {
        float t = 0.0f;
        for (int l = 0; l < NL; ++l)
#pragma unroll
            for (int c = 0; c < 3; ++c) t += msg[(l * NQ + tid) * 3 + c];
        Theta[tid] = t;
    }
    __syncthreads();

    float psq = 0.0f, pc = 0.0f, ps = 0.0f;
    const float* Pb = Rpart + b * PPB * S;
    for (int s = tid; s < S; s += 1024) {          // 2 iterations
        float R = 0.0f;
#pragma unroll
        for (int j = 0; j < PPB; ++j) R += Pb[j * S + s];   // 24 independent loads
        float phi = 0.0f;
#pragma unroll
        for (int q = 0; q < NQ; ++q)
            if ((s >> q) & 1) phi += Theta[q];
        psq += R * R;
        pc  += R * cosf(phi);
        ps  += R * sinf(phi);
    }
#pragma unroll
    for (int off = 32; off >= 1; off >>= 1) {
        psq += __shfl_xor(psq, off, 64);
        pc  += __shfl_xor(pc,  off, 64);
        ps  += __shfl_xor(ps,  off, 64);
    }
    const int lane = tid & 63, wave = tid >> 6;
    if (lane == 0) { red[0][wave] = psq; red[1][wave] = pc; red[2][wave] = ps; }
    __syncthreads();
    if (tid == 0) {
        float sq = 0.f, sc = 0.f, ss = 0.f;
#pragma unroll
        for (int wv = 0; wv < 16; ++wv) { sq += red[0][wv]; sc += red[1][wv]; ss += red[2][wv]; }
        const float norm = fmaxf(sqrtf(sq), 1e-12f);
        rm_sh = sc / (float)S / norm;
        im_sh = ss / (float)S / norm;
    }
    __syncthreads();
    const float rm = rm_sh, im = im_sh;

    // h1[j] = relu(rm * sum(Wo1[j,0:11]) + im * sum(Wo1[j,11:22]) + bo1[j])
    if (tid < 256) {
        float s1 = 0.0f, s2 = 0.0f;
        const float* wrow = Wo1 + tid * (2 * NQ);
#pragma unroll
        for (int k = 0; k < NQ; ++k)       s1 += wrow[k];
#pragma unroll
        for (int k = NQ; k < 2 * NQ; ++k)  s2 += wrow[k];
        h1[tid] = fmaxf(rm * s1 + im * s2 + bo1[tid], 0.0f);
    }
    __syncthreads();
    if (tid < 128) {
        float acc = bo2[tid];
        const float* wrow = Wo2 + tid * 256;
        for (int k = 0; k < 256; ++k) acc += h1[k] * wrow[k];
        h2[tid] = fmaxf(acc, 0.0f);
    }
    __syncthreads();
    if (tid < 64) {
        float acc = bo3[tid];
        const float* wrow = Wo3 + tid * 128;
        for (int k = 0; k < 128; ++k) acc += h2[k] * wrow[k];
        out[b * 64 + tid] = acc;
    }
}

extern "C" void kernel_launch(void* const* d_in, const int* in_sizes, int n_in,
                              void* d_out, int out_size, void* d_ws, size_t ws_size,
                              hipStream_t stream) {
    const float* nf     = (const float*)d_in[0];
    // d_in[1] = edge_indices (unused by the math)
    const float* W1     = (const float*)d_in[2];
    const float* b1     = (const float*)d_in[3];
    const float* W2     = (const float*)d_in[4];
    const float* b2     = (const float*)d_in[5];
    const float* rot    = (const float*)d_in[6];
    const float* ent    = (const float*)d_in[7];
    const float* msg    = (const float*)d_in[8];
    const float* pool_w = (const float*)d_in[9];
    const float* Wo1    = (const float*)d_in[10];
    const float* bo1    = (const float*)d_in[11];
    const float* Wo2    = (const float*)d_in[12];
    const float* bo2    = (const float*)d_in[13];
    const float* Wo3    = (const float*)d_in[14];
    const float* bo3    = (const float*)d_in[15];

    float* Rpart = (float*)d_ws;     // [NB*NA/WPB, S] block partials (plain stores)

    circuit_kernel<<<dim3(NB * NA / WPB), dim3(256), 0, stream>>>(
        nf, W1, b1, W2, b2, rot, ent, pool_w, Rpart);

    pool_mlp_kernel<<<dim3(NB), dim3(1024), 0, stream>>>(
        Rpart, msg, Wo1, bo1, Wo2, bo2, Wo3, bo3, (float*)d_out);
}